// Round 1
// baseline (541.376 us; speedup 1.0000x reference)
//
#include <hip/hip_runtime.h>
#include <hip/hip_bf16.h>
#include <math.h>

#define B_ 32
#define N_ 2048
#define C_ 64
#define M_ 512
#define KNN_ 32
#define RADIUS_ 0.4f
#define RCUT2 0.16016f        // conservative candidate cut (mask re-applied exactly later)
#define GSCALE_ 6.2383246250f
#define TT 4                  // targets per block in main kernel
#define MAXC 256

// ---- shared-memory layout for main kernel (float offsets) ----
#define ZSTR 193              // 192 + 1 pad: breaks stride-192 (16-way) bank conflict
#define ZT   (16*ZSTR)        // 3088 floats per target
#define Z_OFF 0
#define Z_SZ  (TT*ZT)         // 12352
#define Y_OFF (Z_OFF + Z_SZ)  // 12352
#define Y_SZ  (TT*32*16)      // 2048
#define W_OFF (Y_OFF + Y_SZ)  // 14400
#define W_SZ  (TT*32*4)       // 512
#define DEN_OFF (W_OFF + W_SZ)   // 14912
#define DEN_SZ  (TT*4)           // 16
#define WST_OFF (DEN_OFF + DEN_SZ) // 14928
#define WST_BSTR 1032            // 16*64 + 8 pad per band -> 2-way conflicts (free)
#define WST_SZ  (4*WST_BSTR)     // 4128
#define SM_TOTAL (WST_OFF + WST_SZ) // 19056 floats = 76224 B

// =====================================================================
// Kernel 1: radius-filtered exact KNN (wave per target)
// =====================================================================
__global__ __launch_bounds__(256) void knn_kernel(const float* __restrict__ points,
                                                  int* __restrict__ nbr_idx,
                                                  int* __restrict__ nbr_cnt)
{
    __shared__ float px[N_], py[N_], pz[N_];
    __shared__ float cd2[4][MAXC];
    __shared__ int   cidx[4][MAXC];
    const int b = blockIdx.x >> 7;
    const int mbase = (blockIdx.x & 127) * 4;
    const int tid = threadIdx.x;
    const float* pb = points + (size_t)b * N_ * 3;
    for (int i = tid; i < N_; i += 256) {
        px[i] = pb[i*3+0]; py[i] = pb[i*3+1]; pz[i] = pb[i*3+2];
    }
    __syncthreads();
    const int w = tid >> 6, lane = tid & 63;
    const int m = mbase + w;
    const float tx = px[4*m], ty = py[4*m], tz = pz[4*m];
    int base = 0;
    for (int j = 0; j < 32; ++j) {
        int i = j*64 + lane;
        float dx = px[i]-tx, dy = py[i]-ty, dz = pz[i]-tz;
        float d2 = dx*dx + dy*dy + dz*dz;
        bool cand = d2 <= RCUT2;
        unsigned long long mask = __ballot(cand);
        if (cand) {
            int pos = base + __popcll(mask & ((1ull<<lane)-1ull));
            if (pos < MAXC) { cd2[w][pos] = d2; cidx[w][pos] = i; }
        }
        base += __popcll(mask);
    }
    int C = base < MAXC ? base : MAXC;
    const int out_off = (b*M_ + m) * KNN_;
    if (C <= KNN_) {
        if (lane < KNN_) nbr_idx[out_off + lane] = (lane < C) ? cidx[w][lane] : 0;
        if (lane == 0) nbr_cnt[b*M_ + m] = C;
    } else {
        // register-cached candidates (<=4 per lane); removal via per-lane bitmask
        float xv[4];
        #pragma unroll
        for (int s = 0; s < 4; ++s) {
            int q = s*64 + lane;
            xv[s] = (q < C) ? cd2[w][q] : 1e30f;
        }
        unsigned rm = 0;
        for (int r = 0; r < KNN_; ++r) {
            float v = 1e30f; int ci = MAXC;
            #pragma unroll
            for (int s = 0; s < 4; ++s) {
                bool ok = !((rm >> s) & 1u) && (xv[s] < v);
                if (ok) { v = xv[s]; ci = s*64 + lane; }
            }
            #pragma unroll
            for (int off = 32; off >= 1; off >>= 1) {
                float ov = __shfl_xor(v, off);
                int   oi = __shfl_xor(ci, off);
                if (ov < v || (ov == v && oi < ci)) { v = ov; ci = oi; }
            }
            if ((ci & 63) == lane) rm |= 1u << (ci >> 6);
            if (lane == 0) nbr_idx[out_off + r] = cidx[w][ci];
        }
        if (lane == 0) nbr_cnt[b*M_ + m] = KNN_;
    }
}

// =====================================================================
// Kernel 2: fused SH/weights + z-einsum + slab matmul + band norms + max
// =====================================================================
__global__ __launch_bounds__(256) void main_kernel(
    const float* __restrict__ points, const float* __restrict__ feats,
    const float* __restrict__ W0, const float* __restrict__ b0,
    const float* __restrict__ W1, const float* __restrict__ W2, const float* __restrict__ W3,
    const int* __restrict__ nbr_idx, const int* __restrict__ nbr_cnt,
    unsigned int* __restrict__ hmax)
{
    __shared__ __align__(16) float smem[SM_TOTAL];
    __shared__ int sh_nbr[TT][32];
    __shared__ int sh_cnt[TT];
    const int tid = threadIdx.x;
    const int b = blockIdx.x >> 7;
    const int mbase = (blockIdx.x & 127) * TT;

    // P0: neighbor lists
    if (tid < TT*32) {
        int t = tid >> 5, k = tid & 31;
        sh_nbr[t][k] = nbr_idx[(b*M_ + mbase + t)*32 + k];
        if (k == 0) sh_cnt[t] = nbr_cnt[b*M_ + mbase + t];
    }
    __syncthreads();

    // P1: per-neighbor geometry -> Y, raw w
    if (tid < TT*32) {
        int t = tid >> 5, k = tid & 31;
        int m = mbase + t;
        const float* pb = points + (size_t)b * N_ * 3;
        float tx = pb[4*m*3+0], ty = pb[4*m*3+1], tz = pb[4*m*3+2];
        int n = sh_nbr[t][k];
        float x = pb[n*3+0] - tx, y = pb[n*3+1] - ty, z = pb[n*3+2] - tz;
        float d2 = x*x + y*y + z*z;
        float dist = sqrtf(fmaxf(d2, 1e-12f));
        float inv = 1.0f / dist;
        float dx = x*inv, dy = y*inv, dz = z*inv;
        float x2 = dx*dx, y2 = dy*dy, z2 = dz*dz;
        float* Yp = &smem[Y_OFF + (t*32+k)*16];
        Yp[0]  = 0.282095f;
        Yp[1]  = 0.488603f*dy;  Yp[2] = 0.488603f*dz;  Yp[3] = 0.488603f*dx;
        Yp[4]  = 1.092548f*dx*dy;
        Yp[5]  = 1.092548f*dy*dz;
        Yp[6]  = 0.315392f*(3.0f*z2-1.0f);
        Yp[7]  = 1.092548f*dx*dz;
        Yp[8]  = 0.546274f*(x2-y2);
        Yp[9]  = 0.590044f*dy*(3.0f*x2-y2);
        Yp[10] = 2.890611f*dx*dy*dz;
        Yp[11] = 0.457046f*dy*(5.0f*z2-1.0f);
        Yp[12] = 0.373176f*dz*(5.0f*z2-3.0f);
        Yp[13] = 0.457046f*dx*(5.0f*z2-1.0f);
        Yp[14] = 1.445306f*dz*(x2-y2);
        Yp[15] = 0.590044f*dx*(x2-3.0f*y2);
        float dn = dist * (1.0f/RADIUS_);
        bool ok = (k < sh_cnt[t]) && (dn <= 1.0f);
        float* Wp = &smem[W_OFF + (t*32+k)*4];
        #pragma unroll
        for (int s = 0; s < 3; ++s) {
            float dd = dn - 0.5f*(float)s;
            Wp[s] = ok ? __expf(-GSCALE_*dd*dd) : 0.0f;
        }
    }
    __syncthreads();

    // P2: per-(t,s) denominators
    if (tid < TT*4) {
        int t = tid >> 2, s = tid & 3;
        if (s < 3) {
            float acc = 0.f;
            for (int k = 0; k < 32; ++k) acc += smem[W_OFF + (t*32+k)*4 + s];
            smem[DEN_OFF + t*4 + s] = acc + 1e-8f;
        }
    }
    __syncthreads();
    // P2b: normalize (same per-element division as reference)
    if (tid < TT*32) {
        int t = tid >> 5, k = tid & 31;
        #pragma unroll
        for (int s = 0; s < 3; ++s)
            smem[W_OFF + (t*32+k)*4 + s] /= smem[DEN_OFF + t*4 + s];
    }
    __syncthreads();

    // P3: z-einsum. thread = (t, channel jj); coalesced global f loads.
    {
        int t = tid >> 6, jj = tid & 63;
        const float* fb = feats + (size_t)b * N_ * C_;
        float z0[16], z1[16], z2[16];
        #pragma unroll
        for (int p = 0; p < 16; ++p) { z0[p]=0.f; z1[p]=0.f; z2[p]=0.f; }
        float fv = fb[(size_t)sh_nbr[t][0] * C_ + jj];
        for (int k = 0; k < 32; ++k) {
            float fnext = 0.f;
            if (k < 31) fnext = fb[(size_t)sh_nbr[t][k+1] * C_ + jj];
            float w0 = smem[W_OFF + (t*32+k)*4 + 0];
            float w1 = smem[W_OFF + (t*32+k)*4 + 1];
            float w2 = smem[W_OFF + (t*32+k)*4 + 2];
            float g0 = w0*fv, g1 = w1*fv, g2 = w2*fv;
            const float* Yk = &smem[Y_OFF + (t*32+k)*16];
            #pragma unroll
            for (int p = 0; p < 16; ++p) {
                float yv = Yk[p];
                z0[p] = fmaf(yv, g0, z0[p]);
                z1[p] = fmaf(yv, g1, z1[p]);
                z2[p] = fmaf(yv, g2, z2[p]);
            }
            fv = fnext;
        }
        float* zt = &smem[Z_OFF + t*ZT];
        #pragma unroll
        for (int p = 0; p < 16; ++p) {
            zt[p*ZSTR + jj      ] = z0[p];
            zt[p*ZSTR + 64  + jj] = z1[p];
            zt[p*ZSTR + 128 + jj] = z2[p];
        }
    }
    __syncthreads();

    // P4: slab matmul. thread = (t, p, u-quarter); W streamed 16 rows x 4 bands.
    {
        int t = tid >> 6;
        int r = tid & 63;
        int p = r >> 2, uq = r & 3, u0 = uq*16;
        int l = (p==0) ? 0 : (p<4) ? 1 : (p<9) ? 2 : 3;
        const float* Wl_arr[4] = {W0, W1, W2, W3};
        float o[16];
        #pragma unroll
        for (int i = 0; i < 16; ++i) o[i] = 0.f;
        const float* zrow = &smem[Z_OFF + t*ZT + p*ZSTR];
        const int jl_st = tid >> 4, uu = (tid & 15) * 4;
        for (int c = 0; c < 12; ++c) {
            int j0 = c*16;
            #pragma unroll
            for (int it = 0; it < 4; ++it) {
                const float4 v = *(const float4*)(Wl_arr[it] + (j0 + jl_st)*64 + uu);
                *(float4*)&smem[WST_OFF + it*WST_BSTR + jl_st*64 + uu] = v;
            }
            __syncthreads();
            const float* wb = &smem[WST_OFF + l*WST_BSTR];
            #pragma unroll
            for (int jl = 0; jl < 16; ++jl) {
                float zv = zrow[j0 + jl];
                const float* wr = wb + jl*64 + u0;
                #pragma unroll
                for (int i = 0; i < 16; ++i)
                    o[i] = fmaf(zv, wr[i], o[i]);
            }
            __syncthreads();
        }
        if (p == 0) {
            #pragma unroll
            for (int i = 0; i < 16; ++i) o[i] += b0[u0+i];
        }
        // store o into (dead) z region: part[t][p][u] at t*ZT + p*ZSTR + u
        float* prow = &smem[Z_OFF + t*ZT + p*ZSTR + u0];
        #pragma unroll
        for (int i = 0; i < 16; ++i) prow[i] = o[i];
    }
    __syncthreads();

    // P5: band norms -> hb (reuse Y region), block max over t, global atomicMax
    {
        int t = tid >> 6, u = tid & 63;
        const float* pt = &smem[Z_OFF + t*ZT];
        float a0 = pt[0*ZSTR + u];
        float h0 = sqrtf(fmaxf(a0*a0, 1e-8f));
        float s1 = 0.f;
        #pragma unroll
        for (int p = 1; p < 4; ++p) { float a = pt[p*ZSTR + u]; s1 += a*a; }
        float h1 = sqrtf(fmaxf(s1, 1e-8f));
        float s2 = 0.f;
        #pragma unroll
        for (int p = 4; p < 9; ++p) { float a = pt[p*ZSTR + u]; s2 += a*a; }
        float h2 = sqrtf(fmaxf(s2, 1e-8f));
        float s3 = 0.f;
        #pragma unroll
        for (int p = 9; p < 16; ++p) { float a = pt[p*ZSTR + u]; s3 += a*a; }
        float h3 = sqrtf(fmaxf(s3, 1e-8f));
        smem[Y_OFF + (0*TT + t)*64 + u] = h0;
        smem[Y_OFF + (1*TT + t)*64 + u] = h1;
        smem[Y_OFF + (2*TT + t)*64 + u] = h2;
        smem[Y_OFF + (3*TT + t)*64 + u] = h3;
    }
    __syncthreads();
    {
        int l = tid >> 6, u = tid & 63;
        float mx = smem[Y_OFF + (l*TT + 0)*64 + u];
        #pragma unroll
        for (int t = 1; t < TT; ++t) mx = fmaxf(mx, smem[Y_OFF + (l*TT + t)*64 + u]);
        atomicMax(&hmax[b*256 + l*64 + u], __float_as_uint(mx)); // all values > 0
    }
}

// =====================================================================
// Kernel 3: FC head + softmax (one block per batch element)
// =====================================================================
__global__ __launch_bounds__(256) void fc_kernel(
    const unsigned int* __restrict__ hmax,
    const float* __restrict__ Wfc1, const float* __restrict__ bfc1,
    const float* __restrict__ Wfc2, const float* __restrict__ bfc2,
    const float* __restrict__ Wsm, const float* __restrict__ bsm,
    float* __restrict__ out)
{
    __shared__ float h[256], t1[512], t2[256], lg[40];
    const int b = blockIdx.x, tid = threadIdx.x;
    h[tid] = __uint_as_float(hmax[b*256 + tid]);
    __syncthreads();
    #pragma unroll
    for (int rep = 0; rep < 2; ++rep) {
        int u = tid + rep*256;
        float acc = bfc1[u];
        for (int i = 0; i < 256; ++i) acc = fmaf(h[i], Wfc1[i*512 + u], acc);
        t1[u] = fmaxf(acc, 0.f);
    }
    __syncthreads();
    {
        float acc = bfc2[tid];
        for (int i = 0; i < 512; ++i) acc = fmaf(t1[i], Wfc2[i*256 + tid], acc);
        t2[tid] = fmaxf(acc, 0.f);
    }
    __syncthreads();
    if (tid < 40) {
        float acc = bsm[tid];
        for (int i = 0; i < 256; ++i) acc = fmaf(t2[i], Wsm[i*40 + tid], acc);
        lg[tid] = acc;
    }
    __syncthreads();
    if (tid < 64) {
        float x = (tid < 40) ? lg[tid] : -1e30f;
        float mx = x;
        #pragma unroll
        for (int off = 32; off >= 1; off >>= 1) mx = fmaxf(mx, __shfl_xor(mx, off));
        float e = (tid < 40) ? expf(x - mx) : 0.f;
        float s = e;
        #pragma unroll
        for (int off = 32; off >= 1; off >>= 1) s += __shfl_xor(s, off);
        if (tid < 40) out[b*40 + tid] = e / s;
    }
}

extern "C" void kernel_launch(void* const* d_in, const int* in_sizes, int n_in,
                              void* d_out, int out_size, void* d_ws, size_t ws_size,
                              hipStream_t stream)
{
    const float* points = (const float*)d_in[0];
    const float* feats  = (const float*)d_in[1];
    const float* W0   = (const float*)d_in[2];
    const float* b0   = (const float*)d_in[3];
    const float* W1   = (const float*)d_in[4];
    const float* W2   = (const float*)d_in[5];
    const float* W3   = (const float*)d_in[6];
    const float* Wfc1 = (const float*)d_in[7];
    const float* bfc1 = (const float*)d_in[8];
    const float* Wfc2 = (const float*)d_in[9];
    const float* bfc2 = (const float*)d_in[10];
    const float* Wsm  = (const float*)d_in[11];
    const float* bsm  = (const float*)d_in[12];
    float* out = (float*)d_out;

    char* ws = (char*)d_ws;
    int* nbr_idx = (int*)ws;                                    // 16384*32*4 = 2 MB
    int* nbr_cnt = (int*)(ws + 2*1024*1024);                    // 64 KB
    unsigned int* hmax = (unsigned int*)(ws + 2*1024*1024 + 64*1024); // 32 KB

    hipMemsetAsync(hmax, 0, B_*256*sizeof(unsigned int), stream);
    knn_kernel<<<4096, 256, 0, stream>>>(points, nbr_idx, nbr_cnt);
    main_kernel<<<4096, 256, 0, stream>>>(points, feats, W0, b0, W1, W2, W3,
                                          nbr_idx, nbr_cnt, hmax);
    fc_kernel<<<32, 256, 0, stream>>>(hmax, Wfc1, bfc1, Wfc2, bfc2, Wsm, bsm, out);
}